// Round 4
// baseline (1269.313 us; speedup 1.0000x reference)
//
#include <hip/hip_runtime.h>
#include <math.h>

#define NTOK 13824            // 24*24*24
#define MTOT 27648            // B*NTOK
#define BATCH 2
#define CIN 128
#define DMODEL 256
#define NHEAD 8
#define NLAYERS 4
#define DFF 512

typedef float f32x4 __attribute__((ext_vector_type(4)));
typedef __bf16 bf16x8 __attribute__((ext_vector_type(8)));
typedef __attribute__((address_space(1))) void gvoid;
typedef __attribute__((address_space(3))) void lvoid;

// async global->LDS, 16B per lane. LDS dest must be uniform-base + lane*16.
#define GLDS16(g, l) __builtin_amdgcn_global_load_lds((gvoid*)(g), (lvoid*)(l), 16, 0, 0)

__device__ __forceinline__ unsigned short f2bf(float f) {
    unsigned u = __float_as_uint(f);
    return (unsigned short)((u + 0x7FFFu + ((u >> 16) & 1u)) >> 16);
}
__device__ __forceinline__ float bf2f(unsigned short h) {
    return __uint_as_float(((unsigned)h) << 16);
}

// ---------------------------------------------------------------------------
// bf16 MFMA GEMM: C[M x N] = act(A[M x K](bf16) * B[K x N] + bias)
// B supplied TRANSPOSED: Bt[N][K] bf16. 128x128 tile, BK=32, 256 threads,
// global_load_lds(16B) staging (m97 structure).
// ACT: 0 none, 1 relu, 2 gelu(exact). OUTM: 1 = bf16 C only, 2 = f32 + bf16.
// ---------------------------------------------------------------------------
template<int ACT, int OUTM>
__global__ __launch_bounds__(256) void gemm_bf16(
    const unsigned short* __restrict__ A, int lda,
    const unsigned short* __restrict__ Bt, int ldb,
    const float* __restrict__ bias,
    float* __restrict__ Cf, unsigned short* __restrict__ Cb,
    int ldc, int K)
{
    __shared__ __attribute__((aligned(16))) unsigned short As[4096]; // 128 x 32
    __shared__ __attribute__((aligned(16))) unsigned short Bs[4096]; // 128 x 32 (n-major)
    const int t    = threadIdx.x;
    const int lane = t & 63;
    const int wave = t >> 6;
    const int wm = wave & 1, wn = wave >> 1;
    const int m0 = blockIdx.x * 128, n0 = blockIdx.y * 128;

    const int r0   = t >> 2;
    const int koff = (t & 3) * 8;
    const unsigned short* ga0 = A  + (size_t)(m0 + r0)      * lda + koff;
    const unsigned short* ga1 = A  + (size_t)(m0 + r0 + 64) * lda + koff;
    const unsigned short* gb0 = Bt + (size_t)(n0 + r0)      * ldb + koff;
    const unsigned short* gb1 = Bt + (size_t)(n0 + r0 + 64) * ldb + koff;
    unsigned short* la0 = As + t * 8;
    unsigned short* la1 = As + t * 8 + 2048;
    unsigned short* lb0 = Bs + t * 8;
    unsigned short* lb1 = Bs + t * 8 + 2048;

    f32x4 acc[4][4];
    #pragma unroll
    for (int i = 0; i < 4; ++i)
        #pragma unroll
        for (int j = 0; j < 4; ++j) acc[i][j] = (f32x4)0.0f;

    const int fm = lane & 15;
    const int fq = (lane >> 4) * 8;
    const int arow = (wm * 64 + fm) * 32 + fq;   // + i*512
    const int brow = (wn * 64 + fm) * 32 + fq;   // + j*512

    for (int k0 = 0; k0 < K; k0 += 32) {
        GLDS16(ga0 + k0, la0);
        GLDS16(ga1 + k0, la1);
        GLDS16(gb0 + k0, lb0);
        GLDS16(gb1 + k0, lb1);
        __syncthreads();
        bf16x8 af[4], bg[4];
        #pragma unroll
        for (int i = 0; i < 4; ++i) af[i] = *(const bf16x8*)(As + arow + i * 512);
        #pragma unroll
        for (int j = 0; j < 4; ++j) bg[j] = *(const bf16x8*)(Bs + brow + j * 512);
        #pragma unroll
        for (int i = 0; i < 4; ++i)
            #pragma unroll
            for (int j = 0; j < 4; ++j)
                acc[i][j] = __builtin_amdgcn_mfma_f32_16x16x32_bf16(
                    af[i], bg[j], acc[i][j], 0, 0, 0);
        __syncthreads();
    }

    const int cb  = n0 + wn * 64 + fm;
    const int rbs = m0 + wm * 64 + (lane >> 4) * 4;
    #pragma unroll
    for (int j = 0; j < 4; ++j) {
        const int n = cb + j * 16;
        const float bv = bias[n];
        #pragma unroll
        for (int i = 0; i < 4; ++i) {
            #pragma unroll
            for (int r = 0; r < 4; ++r) {
                float v = acc[i][j][r] + bv;
                if (ACT == 1) v = fmaxf(v, 0.0f);
                if (ACT == 2) v = 0.5f * v * (1.0f + erff(v * 0.7071067811865476f));
                const size_t off = (size_t)(rbs + i * 16 + r) * ldc + n;
                if (OUTM == 2) Cf[off] = v;
                Cb[off] = f2bf(v);
            }
        }
    }
}

// ---------------------------------------------------------------------------
// one-shot weight conversion: transpose to [N][K] bf16 + bias concat
// ---------------------------------------------------------------------------
#define CW_QKV  786432   // 4*768*256
#define CW_O   1048576   // + 4*256*256
#define CW_1   1572864   // + 4*512*256
#define CW_2   2097152   // + 4*256*512
#define CW_X   2129920   // + 256*128
#define CW_B   2132992   // + 4*768
__global__ __launch_bounds__(256) void conv_weights(
    const float* __restrict__ Wq, const float* __restrict__ Wk,
    const float* __restrict__ Wv, const float* __restrict__ Wo,
    const float* __restrict__ fw1, const float* __restrict__ fw2,
    const float* __restrict__ Wx_w,
    const float* __restrict__ bq, const float* __restrict__ bk,
    const float* __restrict__ bv,
    unsigned short* __restrict__ wqkv_t, unsigned short* __restrict__ wo_t,
    unsigned short* __restrict__ w1_t, unsigned short* __restrict__ w2_t,
    unsigned short* __restrict__ wx_bf, float* __restrict__ bqkv)
{
    const int e = blockIdx.x * 256 + threadIdx.x;
    if (e < CW_QKV) {
        const int i = e / 196608, r = e % 196608;
        const int n = r / 256, k = r % 256;
        const float* src = (n < 256) ? Wq : (n < 512) ? Wk : Wv;
        wqkv_t[e] = f2bf(src[((size_t)i * 256 + k) * 256 + (n & 255)]);
    } else if (e < CW_O) {
        const int r = e - CW_QKV;
        const int i = r / 65536, rr = r % 65536, n = rr / 256, k = rr % 256;
        wo_t[r] = f2bf(Wo[((size_t)i * 256 + k) * 256 + n]);
    } else if (e < CW_1) {
        const int r = e - CW_O;
        const int i = r / 131072, rr = r % 131072, n = rr / 256, k = rr % 256;
        w1_t[r] = f2bf(fw1[((size_t)i * 256 + k) * 512 + n]);
    } else if (e < CW_2) {
        const int r = e - CW_1;
        const int i = r / 131072, rr = r % 131072, n = rr / 512, k = rr % 512;
        w2_t[r] = f2bf(fw2[((size_t)i * 512 + k) * 256 + n]);
    } else if (e < CW_X) {
        const int r = e - CW_2;
        wx_bf[r] = f2bf(Wx_w[r]);     // Wx_w [out][in] is already B^T layout
    } else if (e < CW_B) {
        const int r = e - CW_X;
        const int i = r / 768, j = r % 768;
        const float v = (j < 256) ? bq[i * 256 + j]
                      : (j < 512) ? bk[i * 256 + j - 256]
                                  : bv[i * 256 + j - 512];
        bqkv[r] = v;
    }
}

// x [B][CIN][NTOK] f32 -> xbf [MTOT][CIN] bf16 (token-major)
__global__ __launch_bounds__(256) void conv_x(
    const float* __restrict__ x, unsigned short* __restrict__ xbf)
{
    const int e = blockIdx.x * 256 + threadIdx.x;     // e < MTOT*128
    const int m = e >> 7, c = e & 127;
    const int b = (m >= NTOK) ? 1 : 0;
    const int n = m - b * NTOK;
    xbf[e] = f2bf(x[((size_t)b * CIN + c) * NTOK + n]);
}

// ---------------------------------------------------------------------------
// q softmax over dk=32, in place on the q-slot of qkv. 8 bf16 per lane,
// 4-lane clusters cover one 32-channel group (xor 1,2 shuffles).
// Writes ex/sum (1/sqrt(dk) folded into ctxwo). grid = MTOT*32/256.
// ---------------------------------------------------------------------------
__global__ __launch_bounds__(256) void qsm_kernel(unsigned short* __restrict__ qkv)
{
    const int g = blockIdx.x * 256 + threadIdx.x;   // < MTOT*32
    const int row = g >> 5;
    const int cg  = g & 31;                          // 8-channel chunk
    unsigned short* p = qkv + (size_t)row * 768 + cg * 8;
    uint4 raw = *(const uint4*)p;
    unsigned short* rp = (unsigned short*)&raw;
    float v[8];
    #pragma unroll
    for (int j = 0; j < 8; ++j) v[j] = bf2f(rp[j]);
    float m = v[0];
    #pragma unroll
    for (int j = 1; j < 8; ++j) m = fmaxf(m, v[j]);
    m = fmaxf(m, __shfl_xor(m, 1, 64));
    m = fmaxf(m, __shfl_xor(m, 2, 64));
    float s = 0.0f;
    #pragma unroll
    for (int j = 0; j < 8; ++j) { v[j] = __expf(v[j] - m); s += v[j]; }
    s += __shfl_xor(s, 1, 64);
    s += __shfl_xor(s, 2, 64);
    const float r = 1.0f / s;
    #pragma unroll
    for (int j = 0; j < 8; ++j) rp[j] = f2bf(v[j] * r);
    *(uint4*)p = raw;
}

// ---------------------------------------------------------------------------
// k softmax stats, phase 1: coalesced row reads, per-chunk partials.
// grid = B*64 (chunk = 216 tokens), block 256 (thread = channel).
// ---------------------------------------------------------------------------
__global__ __launch_bounds__(256) void ksm_part(
    const unsigned short* __restrict__ qkv,
    float* __restrict__ Mp, float* __restrict__ Sp)
{
    const int chunk = blockIdx.x & 63;
    const int b     = blockIdx.x >> 6;
    const int c     = threadIdx.x;
    const unsigned short* base =
        qkv + ((size_t)(b * NTOK + chunk * 216)) * 768 + 256 + c;
    float m = -1e30f, s = 0.0f;
    for (int n = 0; n < 216; ++n) {
        const float v = bf2f(base[(size_t)n * 768]);
        if (v > m) { s = s * __expf(m - v) + 1.0f; m = v; }
        else       { s += __expf(v - m); }
    }
    Mp[blockIdx.x * 256 + c] = m;
    Sp[blockIdx.x * 256 + c] = s;
}

// phase 2: reduce 64 partials per (b, channel). grid = B, block 256.
__global__ __launch_bounds__(256) void ksm_red(
    const float* __restrict__ Mp, const float* __restrict__ Sp,
    float* __restrict__ Mk, float* __restrict__ Sk)
{
    const int b = blockIdx.x, c = threadIdx.x;
    float m = -1e30f, s = 0.0f;
    for (int j = 0; j < 64; ++j) {
        const float m2 = Mp[(b * 64 + j) * 256 + c];
        const float s2 = Sp[(b * 64 + j) * 256 + c];
        const float M = fmaxf(m, m2);
        s = s * __expf(m - M) + s2 * __expf(m2 - M);
        m = M;
    }
    Mk[b * 256 + c] = m;
    Sk[b * 256 + c] = s;
}

// ---------------------------------------------------------------------------
// ctx[b][h][d][e] = sum_n softmaxed_k[n][d] * v[n][e]; k,v bf16 in qkv
// ---------------------------------------------------------------------------
__global__ __launch_bounds__(256) void ctx_kernel(
    const unsigned short* __restrict__ qkv,
    const float* __restrict__ Mk, const float* __restrict__ Sk,
    float* __restrict__ ctx)
{
    const int chunk = blockIdx.x, h = blockIdx.y, b = blockIdx.z;
    const int n0 = chunk * 512;
    const int t = threadIdx.x;
    const int col = t & 31;
    const int d0  = t >> 5;   // 0..7
    __shared__ float ke[32][33], ve[32][33];
    float acc[4] = {0, 0, 0, 0};
    const int gc = h * 32 + col;
    const float Mv   = Mk[b * 256 + gc];
    const float invS = 1.0f / Sk[b * 256 + gc];
    const unsigned short* kb = qkv + (size_t)b * NTOK * 768 + 256;
    const unsigned short* vb = qkv + (size_t)b * NTOK * 768 + 512;

    for (int sub = 0; sub < 16; ++sub) {
        const int nb = n0 + sub * 32;
        __syncthreads();
        #pragma unroll
        for (int e = 0; e < 4; ++e) {
            const int tok = d0 + e * 8;
            const size_t idx = (size_t)(nb + tok) * 768 + gc;
            ke[tok][col] = __expf(bf2f(kb[idx]) - Mv) * invS;
            ve[tok][col] = bf2f(vb[idx]);
        }
        __syncthreads();
        #pragma unroll 8
        for (int tok = 0; tok < 32; ++tok) {
            const float vv = ve[tok][col];
            #pragma unroll
            for (int j = 0; j < 4; ++j)
                acc[j] += ke[tok][d0 + 8 * j] * vv;
        }
    }
    float* cp = ctx + (size_t)(b * 8 + h) * 1024;
    #pragma unroll
    for (int j = 0; j < 4; ++j)
        atomicAdd(&cp[(d0 + 8 * j) * 32 + col], acc[j]);
}

// ---------------------------------------------------------------------------
// W'[b][n][h*32+d] = (1/sqrt(dk)) * sum_e ctx[b][h][d][e] * Wo[h*32+e][n]
// grid (NHEAD, B), block 256 (thread = n). wo_t is [n][k] bf16.
// Output wp in Bt ([N][K]) bf16 layout for gemm_bf16.
// ---------------------------------------------------------------------------
__global__ __launch_bounds__(256) void ctxwo_kernel(
    const float* __restrict__ ctx, const unsigned short* __restrict__ wo_t,
    unsigned short* __restrict__ wp)
{
    const int h = blockIdx.x, b = blockIdx.y;
    const int n = threadIdx.x;
    __shared__ float cl[1024];
    {
        const float* cp = ctx + (size_t)(b * 8 + h) * 1024;
        *(float4*)&cl[n * 4] = *(const float4*)&cp[n * 4];
    }
    __syncthreads();
    float w[32];
    const unsigned short* wop = wo_t + (size_t)n * 256 + h * 32;
    #pragma unroll
    for (int e = 0; e < 32; ++e) w[e] = bf2f(wop[e]);
    unsigned short outv[32];
    #pragma unroll
    for (int d = 0; d < 32; ++d) {
        float acc = 0.0f;
        #pragma unroll
        for (int e = 0; e < 32; ++e) acc += cl[d * 32 + e] * w[e];
        outv[d] = f2bf(acc * 0.17677669529663687f);   // 1/sqrt(32)
    }
    unsigned short* op = wp + (size_t)b * 65536 + (size_t)n * 256 + h * 32;
    #pragma unroll
    for (int d = 0; d < 32; d += 8)
        *(uint4*)(op + d) = *(uint4*)(outv + d);
}

// ---------------------------------------------------------------------------
// t = LayerNorm(t + add(bf16)); writes t f32 in place (+ optional bf16 copy)
// ---------------------------------------------------------------------------
template<int WB>
__global__ __launch_bounds__(256) void ln_kernel(
    float* __restrict__ t, const unsigned short* __restrict__ add,
    const float* __restrict__ g, const float* __restrict__ bta,
    unsigned short* __restrict__ tbf)
{
    const int row = blockIdx.x;
    const int c = threadIdx.x;
    const int lane = c & 63, wave = c >> 6;
    const size_t off = (size_t)row * 256 + c;
    const float v = t[off] + bf2f(add[off]);
    __shared__ float red[8];
    float s = v;
    #pragma unroll
    for (int o = 32; o; o >>= 1) s += __shfl_xor(s, o, 64);
    if (lane == 0) red[wave] = s;
    __syncthreads();
    const float mu = (red[0] + red[1] + red[2] + red[3]) * (1.0f / 256.0f);
    const float dv = v - mu;
    float s2 = dv * dv;
    #pragma unroll
    for (int o = 32; o; o >>= 1) s2 += __shfl_xor(s2, o, 64);
    if (lane == 0) red[wave + 4] = s2;
    __syncthreads();
    const float var = (red[4] + red[5] + red[6] + red[7]) * (1.0f / 256.0f);
    const float o = dv * rsqrtf(var + 1e-6f) * g[c] + bta[c];
    t[off] = o;
    if (WB) tbf[off] = f2bf(o);
}

// ---------------------------------------------------------------------------
// depthwise 3x3x3 conv + residual, register-resident weights + sliding window.
// grid = (24*24, B), block = 256 (thread = channel). No LDS.
// ---------------------------------------------------------------------------
template<int WB>
__global__ __launch_bounds__(256) void posconv_kernel(
    const float* __restrict__ tin, const float* __restrict__ pw,
    const float* __restrict__ pb, float* __restrict__ outp,
    unsigned short* __restrict__ tbfp)
{
    const int hw = blockIdx.x;            // 0..575
    const int b  = blockIdx.y;
    const int hh = hw / 24, ww = hw % 24;
    const int c  = threadIdx.x;

    float w[27];
    #pragma unroll
    for (int k = 0; k < 27; ++k) w[k] = pw[c * 27 + k];
    const float bias = pb[c];

    const float* base = tin + (size_t)b * NTOK * 256 + c;

    const float* colp[9];
    bool colok[9];
    #pragma unroll
    for (int dh = -1; dh <= 1; ++dh)
        #pragma unroll
        for (int dw = -1; dw <= 1; ++dw) {
            const int j = (dh + 1) * 3 + (dw + 1);
            const int h2 = hh + dh, w2 = ww + dw;
            colok[j] = ((unsigned)h2 < 24u) & ((unsigned)w2 < 24u);
            colp[j] = base + (size_t)((h2 * 24 + w2) * 24) * 256;
        }

    float win[9][3];
    #pragma unroll
    for (int j = 0; j < 9; ++j) {
        win[j][0] = 0.0f;
        win[j][1] = colok[j] ? colp[j][0] : 0.0f;
    }

    float* ob = outp + ((size_t)b * NTOK + (size_t)hw * 24) * 256 + c;
    unsigned short* tb = WB ? (tbfp + ((size_t)b * NTOK + (size_t)hw * 24) * 256 + c)
                            : (unsigned short*)nullptr;

    for (int d = 0; d < 24; ++d) {
        #pragma unroll
        for (int j = 0; j < 9; ++j)
            win[j][2] = (colok[j] && d < 23) ? colp[j][(d + 1) * 256] : 0.0f;

        float acc = bias + win[4][1];
        #pragma unroll
        for (int j = 0; j < 9; ++j) {
            acc += w[j * 3 + 0] * win[j][0];
            acc += w[j * 3 + 1] * win[j][1];
            acc += w[j * 3 + 2] * win[j][2];
        }
        ob[d * 256] = acc;
        if (WB) tb[d * 256] = f2bf(acc);

        #pragma unroll
        for (int j = 0; j < 9; ++j) { win[j][0] = win[j][1]; win[j][1] = win[j][2]; }
    }
}

// ---------------------------------------------------------------------------
// final transpose: t [MTOT][256] f32 -> out [B][256][NTOK] (LDS tiled)
// ---------------------------------------------------------------------------
__global__ __launch_bounds__(256) void tr_out(
    const float* __restrict__ tin, float* __restrict__ outp)
{
    __shared__ float tile[32][33];
    const int m0 = blockIdx.x * 32;
    const int c0 = blockIdx.y * 32;
    const int t = threadIdx.x;
    const int tc = t & 31, tr = t >> 5;
    #pragma unroll
    for (int r = 0; r < 4; ++r)
        tile[tr + r * 8][tc] = tin[(size_t)(m0 + tr + r * 8) * 256 + c0 + tc];
    __syncthreads();
    const int b = (m0 >= NTOK) ? 1 : 0;
    const int n0 = m0 - b * NTOK;
    #pragma unroll
    for (int r = 0; r < 4; ++r)
        outp[((size_t)b * 256 + c0 + tr + r * 8) * NTOK + n0 + tc] = tile[tc][tr + r * 8];
}

// ---------------------------------------------------------------------------
// launch
// ---------------------------------------------------------------------------
extern "C" void kernel_launch(void* const* d_in, const int* in_sizes, int n_in,
                              void* d_out, int out_size, void* d_ws, size_t ws_size,
                              hipStream_t stream)
{
    (void)in_sizes; (void)n_in; (void)out_size; (void)ws_size;
    const float* x     = (const float*)d_in[0];
    const float* Wx_w  = (const float*)d_in[1];
    const float* Wx_b  = (const float*)d_in[2];
    const float* Wq    = (const float*)d_in[3];
    const float* bq    = (const float*)d_in[4];
    const float* Wk    = (const float*)d_in[5];
    const float* bk    = (const float*)d_in[6];
    const float* Wv    = (const float*)d_in[7];
    const float* bv    = (const float*)d_in[8];
    const float* Wo    = (const float*)d_in[9];
    const float* bo    = (const float*)d_in[10];
    const float* ln1_g = (const float*)d_in[11];
    const float* ln1_b = (const float*)d_in[12];
    const float* ln2_g = (const float*)d_in[13];
    const float* ln2_b = (const float*)d_in[14];
    const float* fw1   = (const float*)d_in[15];
    const float* fb1   = (const float*)d_in[16];
    const float* fw2   = (const float*)d_in[17];
    const float* fb2   = (const float*)d_in[18];
    const float* pw    = (const float*)d_in[19];
    const float* pb    = (const float*)d_in[20];
    float* out = (float*)d_out;

    char* p = (char*)d_ws;
    float* tA            = (float*)p;          p += (size_t)MTOT * 256 * 4;
    float* tB            = (float*)p;          p += (size_t)MTOT * 256 * 4;
    unsigned short* tbf  = (unsigned short*)p; p += (size_t)MTOT * 256 * 2;
    unsigned short* qkv  = (unsigned short*)p; p += (size_t)MTOT * 768 * 2;
    unsigned short* hbf  = (unsigned short*)p; p += (size_t)MTOT * 512 * 2;
    unsigned short* ob   = (unsigned short*)p; p += (size_t)MTOT * 256 * 2;
    unsigned short* xbf  = (unsigned short*)p; p += (size_t)MTOT * 128 * 2;
    unsigned short* wqkv_t = (unsigned short*)p; p += (size_t)786432 * 2;
    unsigned short* wo_t   = (unsigned short*)p; p += (size_t)262144 * 2;
    unsigned short* w1_t   = (unsigned short*)p; p += (size_t)524288 * 2;
    unsigned short* w2_t   = (unsigned short*)p; p += (size_t)524288 * 2;
    unsigned short* wx_bf  = (unsigned short*)p; p += (size_t)32768 * 2;
    unsigned short* wp     = (unsigned short*)p; p += (size_t)BATCH * 65536 * 2;
    float* bqkv = (float*)p; p += 3072 * 4;
    float* ctx  = (float*)p; p += 16384 * 4;
    float* Mk   = (float*)p; p += 512 * 4;
    float* Sk   = (float*)p; p += 512 * 4;
    float* Mp   = (float*)p; p += 128 * 256 * 4;
    float* Sp   = (float*)p; p += 128 * 256 * 4;

    hipLaunchKernelGGL(conv_weights, dim3(8333), dim3(256), 0, stream,
                       Wq, Wk, Wv, Wo, fw1, fw2, Wx_w, bq, bk, bv,
                       wqkv_t, wo_t, w1_t, w2_t, wx_bf, bqkv);
    hipLaunchKernelGGL(conv_x, dim3(13824), dim3(256), 0, stream, x, xbf);

    // input 1x1x1 conv + relu -> tA f32 + tbf bf16
    hipLaunchKernelGGL((gemm_bf16<1, 2>), dim3(216, 2), dim3(256), 0, stream,
                       xbf, CIN, wx_bf, CIN, Wx_b, tA, tbf, 256, CIN);

    for (int i = 0; i < NLAYERS; ++i) {
        float* tin  = (i & 1) ? tB : tA;
        float* tout = (i & 1) ? tA : tB;

        // fused QKV: [M,256] x [256,768]
        hipLaunchKernelGGL((gemm_bf16<0, 1>), dim3(216, 6), dim3(256), 0, stream,
                           tbf, 256, wqkv_t + (size_t)i * 196608, 256,
                           bqkv + i * 768, nullptr, qkv, 768, 256);

        // k softmax stats (coalesced two-phase)
        hipLaunchKernelGGL(ksm_part, dim3(BATCH * 64), dim3(256), 0, stream, qkv, Mp, Sp);
        hipLaunchKernelGGL(ksm_red, dim3(BATCH), dim3(256), 0, stream, Mp, Sp, Mk, Sk);
        hipMemsetAsync(ctx, 0, 16384 * sizeof(float), stream);
        hipLaunchKernelGGL(ctx_kernel, dim3(27, NHEAD, BATCH), dim3(256), 0, stream,
                           qkv, Mk, Sk, ctx);

        // q softmax in place + W' = ctx @ Wo (per batch)
        hipLaunchKernelGGL(qsm_kernel, dim3(3456), dim3(256), 0, stream, qkv);
        hipLaunchKernelGGL(ctxwo_kernel, dim3(NHEAD, BATCH), dim3(256), 0, stream,
                           ctx, wo_t + (size_t)i * 65536, wp);

        // o_proj = qs @ W' + bo  (per batch; replaces ohead + Wo GEMM)
        for (int b = 0; b < BATCH; ++b)
            hipLaunchKernelGGL((gemm_bf16<0, 1>), dim3(108, 2), dim3(256), 0, stream,
                               qkv + (size_t)b * NTOK * 768, 768,
                               wp + (size_t)b * 65536, 256,
                               bo + i * 256, nullptr,
                               ob + (size_t)b * NTOK * 256, 256, 256);

        hipLaunchKernelGGL((ln_kernel<1>), dim3(MTOT), dim3(256), 0, stream,
                           tin, ob, ln1_g + i * 256, ln1_b + i * 256, tbf);

        // FFN
        hipLaunchKernelGGL((gemm_bf16<2, 1>), dim3(216, 4), dim3(256), 0, stream,
                           tbf, 256, w1_t + (size_t)i * 131072, 256,
                           fb1 + i * 512, nullptr, hbf, 512, 256);
        hipLaunchKernelGGL((gemm_bf16<0, 1>), dim3(216, 2), dim3(256), 0, stream,
                           hbf, 512, w2_t + (size_t)i * 131072, 512,
                           fb2 + i * 256, nullptr, ob, 256, 512);
        hipLaunchKernelGGL((ln_kernel<0>), dim3(MTOT), dim3(256), 0, stream,
                           tin, ob, ln2_g + i * 256, ln2_b + i * 256, nullptr);

        // depthwise conv + residual -> tout f32 (+ tbf bf16 except last layer)
        if (i < NLAYERS - 1)
            hipLaunchKernelGGL((posconv_kernel<1>), dim3(576, BATCH), dim3(256), 0, stream,
                               tin, pw + (size_t)i * 6912, pb + i * 256, tout, tbf);
        else
            hipLaunchKernelGGL((posconv_kernel<0>), dim3(576, BATCH), dim3(256), 0, stream,
                               tin, pw + (size_t)i * 6912, pb + i * 256, tout, nullptr);
    }

    // layer 3 wrote tA
    hipLaunchKernelGGL(tr_out, dim3(MTOT / 32, 8), dim3(256), 0, stream, tA, out);
}

// Round 5
// 1018.742 us; speedup vs baseline: 1.2460x; 1.2460x over previous
//
#include <hip/hip_runtime.h>
#include <math.h>

#define NTOK 13824            // 24*24*24
#define MTOT 27648            // B*NTOK
#define BATCH 2
#define CIN 128
#define DMODEL 256
#define NHEAD 8
#define NLAYERS 4
#define DFF 512

typedef float f32x4 __attribute__((ext_vector_type(4)));
typedef __bf16 bf16x8 __attribute__((ext_vector_type(8)));
typedef __attribute__((address_space(1))) void gvoid;
typedef __attribute__((address_space(3))) void lvoid;

// async global->LDS, 16B per lane. LDS dest must be uniform-base + lane*16.
#define GLDS16(g, l) __builtin_amdgcn_global_load_lds((gvoid*)(g), (lvoid*)(l), 16, 0, 0)

__device__ __forceinline__ unsigned short f2bf(float f) {
    unsigned u = __float_as_uint(f);
    return (unsigned short)((u + 0x7FFFu + ((u >> 16) & 1u)) >> 16);
}
__device__ __forceinline__ float bf2f(unsigned short h) {
    return __uint_as_float(((unsigned)h) << 16);
}

// ---------------------------------------------------------------------------
// bf16 MFMA GEMM: C[M x N] = act(A[M x K](bf16) * B[K x N] + bias)
// B supplied TRANSPOSED: Bt[N][K] bf16. 128x128 tile, BK=32, 256 threads,
// global_load_lds(16B) staging (m97 structure). blockIdx.z batches with
// element strides sA/sB/sC (0 for unbatched).
// ACT: 0 none, 1 relu, 2 gelu(exact). OUTM: 1 = bf16 C only, 2 = f32 + bf16.
// ---------------------------------------------------------------------------
template<int ACT, int OUTM>
__global__ __launch_bounds__(256) void gemm_bf16(
    const unsigned short* __restrict__ A, int lda,
    const unsigned short* __restrict__ Bt, int ldb,
    const float* __restrict__ bias,
    float* __restrict__ Cf, unsigned short* __restrict__ Cb,
    int ldc, int K, long sA, long sB, long sC)
{
    A  += (size_t)blockIdx.z * sA;
    Bt += (size_t)blockIdx.z * sB;
    if (OUTM == 2) Cf += (size_t)blockIdx.z * sC;
    Cb += (size_t)blockIdx.z * sC;

    __shared__ __attribute__((aligned(16))) unsigned short As[4096]; // 128 x 32
    __shared__ __attribute__((aligned(16))) unsigned short Bs[4096]; // 128 x 32 (n-major)
    const int t    = threadIdx.x;
    const int lane = t & 63;
    const int wave = t >> 6;
    const int wm = wave & 1, wn = wave >> 1;
    const int m0 = blockIdx.x * 128, n0 = blockIdx.y * 128;

    const int r0   = t >> 2;
    const int koff = (t & 3) * 8;
    const unsigned short* ga0 = A  + (size_t)(m0 + r0)      * lda + koff;
    const unsigned short* ga1 = A  + (size_t)(m0 + r0 + 64) * lda + koff;
    const unsigned short* gb0 = Bt + (size_t)(n0 + r0)      * ldb + koff;
    const unsigned short* gb1 = Bt + (size_t)(n0 + r0 + 64) * ldb + koff;
    unsigned short* la0 = As + t * 8;
    unsigned short* la1 = As + t * 8 + 2048;
    unsigned short* lb0 = Bs + t * 8;
    unsigned short* lb1 = Bs + t * 8 + 2048;

    f32x4 acc[4][4];
    #pragma unroll
    for (int i = 0; i < 4; ++i)
        #pragma unroll
        for (int j = 0; j < 4; ++j) acc[i][j] = (f32x4)0.0f;

    const int fm = lane & 15;
    const int fq = (lane >> 4) * 8;
    const int arow = (wm * 64 + fm) * 32 + fq;   // + i*512
    const int brow = (wn * 64 + fm) * 32 + fq;   // + j*512

    for (int k0 = 0; k0 < K; k0 += 32) {
        GLDS16(ga0 + k0, la0);
        GLDS16(ga1 + k0, la1);
        GLDS16(gb0 + k0, lb0);
        GLDS16(gb1 + k0, lb1);
        __syncthreads();
        bf16x8 af[4], bg[4];
        #pragma unroll
        for (int i = 0; i < 4; ++i) af[i] = *(const bf16x8*)(As + arow + i * 512);
        #pragma unroll
        for (int j = 0; j < 4; ++j) bg[j] = *(const bf16x8*)(Bs + brow + j * 512);
        #pragma unroll
        for (int i = 0; i < 4; ++i)
            #pragma unroll
            for (int j = 0; j < 4; ++j)
                acc[i][j] = __builtin_amdgcn_mfma_f32_16x16x32_bf16(
                    af[i], bg[j], acc[i][j], 0, 0, 0);
        __syncthreads();
    }

    const int cb  = n0 + wn * 64 + fm;
    const int rbs = m0 + wm * 64 + (lane >> 4) * 4;
    #pragma unroll
    for (int j = 0; j < 4; ++j) {
        const int n = cb + j * 16;
        const float bv = bias[n];
        #pragma unroll
        for (int i = 0; i < 4; ++i) {
            #pragma unroll
            for (int r = 0; r < 4; ++r) {
                float v = acc[i][j][r] + bv;
                if (ACT == 1) v = fmaxf(v, 0.0f);
                if (ACT == 2) v = 0.5f * v * (1.0f + erff(v * 0.7071067811865476f));
                const size_t off = (size_t)(rbs + i * 16 + r) * ldc + n;
                if (OUTM == 2) Cf[off] = v;
                Cb[off] = f2bf(v);
            }
        }
    }
}

// ---------------------------------------------------------------------------
// one-shot weight conversion: transpose to [N][K] bf16 + bias concat
// ---------------------------------------------------------------------------
#define CW_QKV  786432   // 4*768*256
#define CW_O   1048576   // + 4*256*256
#define CW_1   1572864   // + 4*512*256
#define CW_2   2097152   // + 4*256*512
#define CW_X   2129920   // + 256*128
#define CW_B   2132992   // + 4*768
__global__ __launch_bounds__(256) void conv_weights(
    const float* __restrict__ Wq, const float* __restrict__ Wk,
    const float* __restrict__ Wv, const float* __restrict__ Wo,
    const float* __restrict__ fw1, const float* __restrict__ fw2,
    const float* __restrict__ Wx_w,
    const float* __restrict__ bq, const float* __restrict__ bk,
    const float* __restrict__ bv,
    unsigned short* __restrict__ wqkv_t, unsigned short* __restrict__ wo_t,
    unsigned short* __restrict__ w1_t, unsigned short* __restrict__ w2_t,
    unsigned short* __restrict__ wx_bf, float* __restrict__ bqkv)
{
    const int e = blockIdx.x * 256 + threadIdx.x;
    if (e < CW_QKV) {
        const int i = e / 196608, r = e % 196608;
        const int n = r / 256, k = r % 256;
        const float* src = (n < 256) ? Wq : (n < 512) ? Wk : Wv;
        wqkv_t[e] = f2bf(src[((size_t)i * 256 + k) * 256 + (n & 255)]);
    } else if (e < CW_O) {
        const int r = e - CW_QKV;
        const int i = r / 65536, rr = r % 65536, n = rr / 256, k = rr % 256;
        wo_t[r] = f2bf(Wo[((size_t)i * 256 + k) * 256 + n]);
    } else if (e < CW_1) {
        const int r = e - CW_O;
        const int i = r / 131072, rr = r % 131072, n = rr / 256, k = rr % 256;
        w1_t[r] = f2bf(fw1[((size_t)i * 256 + k) * 512 + n]);
    } else if (e < CW_2) {
        const int r = e - CW_1;
        const int i = r / 131072, rr = r % 131072, n = rr / 512, k = rr % 512;
        w2_t[r] = f2bf(fw2[((size_t)i * 512 + k) * 256 + n]);
    } else if (e < CW_X) {
        const int r = e - CW_2;
        wx_bf[r] = f2bf(Wx_w[r]);     // Wx_w [out][in] is already B^T layout
    } else if (e < CW_B) {
        const int r = e - CW_X;
        const int i = r / 768, j = r % 768;
        const float v = (j < 256) ? bq[i * 256 + j]
                      : (j < 512) ? bk[i * 256 + j - 256]
                                  : bv[i * 256 + j - 512];
        bqkv[r] = v;
    }
}

// ---------------------------------------------------------------------------
// x [B][CIN][NTOK] f32 -> xbf [(b,n)][CIN] bf16, LDS 32x32 tile transpose.
// grid (NTOK/32, CIN/32, B), block 256. Coalesced read and write.
// ---------------------------------------------------------------------------
__global__ __launch_bounds__(256) void conv_x(
    const float* __restrict__ x, unsigned short* __restrict__ xbf)
{
    __shared__ float tile[32][33];
    const int n0 = blockIdx.x * 32;
    const int c0 = blockIdx.y * 32;
    const int b  = blockIdx.z;
    const int t = threadIdx.x;
    const int tn = t & 31, tc = t >> 5;
    #pragma unroll
    for (int p = 0; p < 4; ++p)
        tile[tc + p * 8][tn] =
            x[((size_t)(b * CIN + c0 + tc + p * 8)) * NTOK + n0 + tn];
    __syncthreads();
    const int cc = t & 31, nr = t >> 5;
    #pragma unroll
    for (int p = 0; p < 4; ++p)
        xbf[((size_t)(b * NTOK + n0 + nr + p * 8)) * CIN + c0 + cc] =
            f2bf(tile[cc][nr + p * 8]);
}

// ---------------------------------------------------------------------------
// q softmax over dk=32, in place on the q-slot of qkv. 8 bf16 per lane,
// 4-lane clusters cover one 32-channel group (xor 1,2 shuffles).
// Writes ex/sum (1/sqrt(dk) folded into ctxwo). grid = MTOT*32/256.
// ---------------------------------------------------------------------------
__global__ __launch_bounds__(256) void qsm_kernel(unsigned short* __restrict__ qkv)
{
    const int g = blockIdx.x * 256 + threadIdx.x;   // < MTOT*32
    const int row = g >> 5;
    const int cg  = g & 31;                          // 8-channel chunk
    unsigned short* p = qkv + (size_t)row * 768 + cg * 8;
    uint4 raw = *(const uint4*)p;
    unsigned short* rp = (unsigned short*)&raw;
    float v[8];
    #pragma unroll
    for (int j = 0; j < 8; ++j) v[j] = bf2f(rp[j]);
    float m = v[0];
    #pragma unroll
    for (int j = 1; j < 8; ++j) m = fmaxf(m, v[j]);
    m = fmaxf(m, __shfl_xor(m, 1, 64));
    m = fmaxf(m, __shfl_xor(m, 2, 64));
    float s = 0.0f;
    #pragma unroll
    for (int j = 0; j < 8; ++j) { v[j] = __expf(v[j] - m); s += v[j]; }
    s += __shfl_xor(s, 1, 64);
    s += __shfl_xor(s, 2, 64);
    const float r = 1.0f / s;
    #pragma unroll
    for (int j = 0; j < 8; ++j) rp[j] = f2bf(v[j] * r);
    *(uint4*)p = raw;
}

// ---------------------------------------------------------------------------
// ctx_unnorm[b][h][d][e] = sum_n exp(k[n][d]) * v[n][e]  (no max shift;
// |k| << 80 so f32 exp is safe). Also accumulates Sk[b][d] = sum_n exp(k[n][d])
// via atomics (each k element is loaded exactly once across the grid).
// ctx and Sk must be pre-zeroed.
// ---------------------------------------------------------------------------
__global__ __launch_bounds__(256) void ctx_kernel(
    const unsigned short* __restrict__ qkv,
    float* __restrict__ ctx, float* __restrict__ Sk)
{
    const int chunk = blockIdx.x, h = blockIdx.y, b = blockIdx.z;
    const int n0 = chunk * 512;
    const int t = threadIdx.x;
    const int col = t & 31;
    const int d0  = t >> 5;   // 0..7
    __shared__ float ke[32][33], ve[32][33];
    float acc[4] = {0, 0, 0, 0};
    float ssum = 0.0f;
    const int gc = h * 32 + col;
    const unsigned short* kb = qkv + (size_t)b * NTOK * 768 + 256;
    const unsigned short* vb = qkv + (size_t)b * NTOK * 768 + 512;

    for (int sub = 0; sub < 16; ++sub) {
        const int nb = n0 + sub * 32;
        __syncthreads();
        #pragma unroll
        for (int e = 0; e < 4; ++e) {
            const int tok = d0 + e * 8;
            const size_t idx = (size_t)(nb + tok) * 768 + gc;
            const float ek = __expf(bf2f(kb[idx]));
            ke[tok][col] = ek;
            ssum += ek;
            ve[tok][col] = bf2f(vb[idx]);
        }
        __syncthreads();
        #pragma unroll 8
        for (int tok = 0; tok < 32; ++tok) {
            const float vv = ve[tok][col];
            #pragma unroll
            for (int j = 0; j < 4; ++j)
                acc[j] += ke[tok][d0 + 8 * j] * vv;
        }
    }
    atomicAdd(&Sk[b * 256 + gc], ssum);
    float* cp = ctx + (size_t)(b * 8 + h) * 1024;
    #pragma unroll
    for (int j = 0; j < 4; ++j)
        atomicAdd(&cp[(d0 + 8 * j) * 32 + col], acc[j]);
}

// ---------------------------------------------------------------------------
// W'[b][n][h*32+d] = (1/sqrt(dk)) * (1/Sk[d]) * sum_e ctx[b][h][d][e] * Wo[h*32+e][n]
// grid (NHEAD, B), block 256 (thread = n). wo_t is [n][k] bf16.
// Output wp in Bt ([N][K]) bf16 layout for gemm_bf16.
// ---------------------------------------------------------------------------
__global__ __launch_bounds__(256) void ctxwo_kernel(
    const float* __restrict__ ctx, const float* __restrict__ Sk,
    const unsigned short* __restrict__ wo_t, unsigned short* __restrict__ wp)
{
    const int h = blockIdx.x, b = blockIdx.y;
    const int n = threadIdx.x;
    __shared__ float cl[1024];
    __shared__ float sdk[32];
    {
        const float* cp = ctx + (size_t)(b * 8 + h) * 1024;
        *(float4*)&cl[n * 4] = *(const float4*)&cp[n * 4];
    }
    if (n < 32) sdk[n] = 0.17677669529663687f / Sk[b * 256 + h * 32 + n];
    __syncthreads();
    float w[32];
    const unsigned short* wop = wo_t + (size_t)n * 256 + h * 32;
    #pragma unroll
    for (int e = 0; e < 32; ++e) w[e] = bf2f(wop[e]);
    unsigned short outv[32];
    #pragma unroll
    for (int d = 0; d < 32; ++d) {
        float acc = 0.0f;
        #pragma unroll
        for (int e = 0; e < 32; ++e) acc += cl[d * 32 + e] * w[e];
        outv[d] = f2bf(acc * sdk[d]);
    }
    unsigned short* op = wp + (size_t)b * 65536 + (size_t)n * 256 + h * 32;
    #pragma unroll
    for (int d = 0; d < 32; d += 8)
        *(uint4*)(op + d) = *(uint4*)(outv + d);
}

// ---------------------------------------------------------------------------
// t = LayerNorm(t + add(bf16)); writes t f32 in place (+ optional bf16 copy)
// ---------------------------------------------------------------------------
template<int WB>
__global__ __launch_bounds__(256) void ln_kernel(
    float* __restrict__ t, const unsigned short* __restrict__ add,
    const float* __restrict__ g, const float* __restrict__ bta,
    unsigned short* __restrict__ tbf)
{
    const int row = blockIdx.x;
    const int c = threadIdx.x;
    const int lane = c & 63, wave = c >> 6;
    const size_t off = (size_t)row * 256 + c;
    const float v = t[off] + bf2f(add[off]);
    __shared__ float red[8];
    float s = v;
    #pragma unroll
    for (int o = 32; o; o >>= 1) s += __shfl_xor(s, o, 64);
    if (lane == 0) red[wave] = s;
    __syncthreads();
    const float mu = (red[0] + red[1] + red[2] + red[3]) * (1.0f / 256.0f);
    const float dv = v - mu;
    float s2 = dv * dv;
    #pragma unroll
    for (int o = 32; o; o >>= 1) s2 += __shfl_xor(s2, o, 64);
    if (lane == 0) red[wave + 4] = s2;
    __syncthreads();
    const float var = (red[4] + red[5] + red[6] + red[7]) * (1.0f / 256.0f);
    const float o = dv * rsqrtf(var + 1e-6f) * g[c] + bta[c];
    t[off] = o;
    if (WB) tbf[off] = f2bf(o);
}

// ---------------------------------------------------------------------------
// depthwise 3x3x3 conv + residual, register-resident weights + sliding window.
// grid = (24*24, B), block = 256 (thread = channel). No LDS.
// ---------------------------------------------------------------------------
template<int WB>
__global__ __launch_bounds__(256) void posconv_kernel(
    const float* __restrict__ tin, const float* __restrict__ pw,
    const float* __restrict__ pb, float* __restrict__ outp,
    unsigned short* __restrict__ tbfp)
{
    const int hw = blockIdx.x;            // 0..575
    const int b  = blockIdx.y;
    const int hh = hw / 24, ww = hw % 24;
    const int c  = threadIdx.x;

    float w[27];
    #pragma unroll
    for (int k = 0; k < 27; ++k) w[k] = pw[c * 27 + k];
    const float bias = pb[c];

    const float* base = tin + (size_t)b * NTOK * 256 + c;

    const float* colp[9];
    bool colok[9];
    #pragma unroll
    for (int dh = -1; dh <= 1; ++dh)
        #pragma unroll
        for (int dw = -1; dw <= 1; ++dw) {
            const int j = (dh + 1) * 3 + (dw + 1);
            const int h2 = hh + dh, w2 = ww + dw;
            colok[j] = ((unsigned)h2 < 24u) & ((unsigned)w2 < 24u);
            colp[j] = base + (size_t)((h2 * 24 + w2) * 24) * 256;
        }

    float win[9][3];
    #pragma unroll
    for (int j = 0; j < 9; ++j) {
        win[j][0] = 0.0f;
        win[j][1] = colok[j] ? colp[j][0] : 0.0f;
    }

    float* ob = outp + ((size_t)b * NTOK + (size_t)hw * 24) * 256 + c;
    unsigned short* tb = WB ? (tbfp + ((size_t)b * NTOK + (size_t)hw * 24) * 256 + c)
                            : (unsigned short*)nullptr;

    for (int d = 0; d < 24; ++d) {
        #pragma unroll
        for (int j = 0; j < 9; ++j)
            win[j][2] = (colok[j] && d < 23) ? colp[j][(d + 1) * 256] : 0.0f;

        float acc = bias + win[4][1];
        #pragma unroll
        for (int j = 0; j < 9; ++j) {
            acc += w[j * 3 + 0] * win[j][0];
            acc += w[j * 3 + 1] * win[j][1];
            acc += w[j * 3 + 2] * win[j][2];
        }
        ob[d * 256] = acc;
        if (WB) tb[d * 256] = f2bf(acc);

        #pragma unroll
        for (int j = 0; j < 9; ++j) { win[j][0] = win[j][1]; win[j][1] = win[j][2]; }
    }
}

// ---------------------------------------------------------------------------
// final transpose: t [MTOT][256] f32 -> out [B][256][NTOK] (LDS tiled)
// ---------------------------------------------------------------------------
__global__ __launch_bounds__(256) void tr_out(
    const float* __restrict__ tin, float* __restrict__ outp)
{
    __shared__ float tile[32][33];
    const int m0 = blockIdx.x * 32;
    const int c0 = blockIdx.y * 32;
    const int t = threadIdx.x;
    const int tc = t & 31, tr = t >> 5;
    #pragma unroll
    for (int r = 0; r < 4; ++r)
        tile[tr + r * 8][tc] = tin[(size_t)(m0 + tr + r * 8) * 256 + c0 + tc];
    __syncthreads();
    const int b = (m0 >= NTOK) ? 1 : 0;
    const int n0 = m0 - b * NTOK;
    #pragma unroll
    for (int r = 0; r < 4; ++r)
        outp[((size_t)b * 256 + c0 + tr + r * 8) * NTOK + n0 + tc] = tile[tc][tr + r * 8];
}

// ---------------------------------------------------------------------------
// launch
// ---------------------------------------------------------------------------
extern "C" void kernel_launch(void* const* d_in, const int* in_sizes, int n_in,
                              void* d_out, int out_size, void* d_ws, size_t ws_size,
                              hipStream_t stream)
{
    (void)in_sizes; (void)n_in; (void)out_size; (void)ws_size;
    const float* x     = (const float*)d_in[0];
    const float* Wx_w  = (const float*)d_in[1];
    const float* Wx_b  = (const float*)d_in[2];
    const float* Wq    = (const float*)d_in[3];
    const float* bq    = (const float*)d_in[4];
    const float* Wk    = (const float*)d_in[5];
    const float* bk    = (const float*)d_in[6];
    const float* Wv    = (const float*)d_in[7];
    const float* bv    = (const float*)d_in[8];
    const float* Wo    = (const float*)d_in[9];
    const float* bo    = (const float*)d_in[10];
    const float* ln1_g = (const float*)d_in[11];
    const float* ln1_b = (const float*)d_in[12];
    const float* ln2_g = (const float*)d_in[13];
    const float* ln2_b = (const float*)d_in[14];
    const float* fw1   = (const float*)d_in[15];
    const float* fb1   = (const float*)d_in[16];
    const float* fw2   = (const float*)d_in[17];
    const float* fb2   = (const float*)d_in[18];
    const float* pw    = (const float*)d_in[19];
    const float* pb    = (const float*)d_in[20];
    float* out = (float*)d_out;

    char* p = (char*)d_ws;
    float* tA            = (float*)p;          p += (size_t)MTOT * 256 * 4;
    float* tB            = (float*)p;          p += (size_t)MTOT * 256 * 4;
    unsigned short* tbf  = (unsigned short*)p; p += (size_t)MTOT * 256 * 2;
    unsigned short* qkv  = (unsigned short*)p; p += (size_t)MTOT * 768 * 2;
    unsigned short* hbf  = (unsigned short*)p; p += (size_t)MTOT * 512 * 2;
    unsigned short* ob   = (unsigned short*)p; p += (size_t)MTOT * 256 * 2;
    unsigned short* xbf  = (unsigned short*)p; p += (size_t)MTOT * 128 * 2;
    unsigned short* wqkv_t = (unsigned short*)p; p += (size_t)786432 * 2;
    unsigned short* wo_t   = (unsigned short*)p; p += (size_t)262144 * 2;
    unsigned short* w1_t   = (unsigned short*)p; p += (size_t)524288 * 2;
    unsigned short* w2_t   = (unsigned short*)p; p += (size_t)524288 * 2;
    unsigned short* wx_bf  = (unsigned short*)p; p += (size_t)32768 * 2;
    unsigned short* wp     = (unsigned short*)p; p += (size_t)BATCH * 65536 * 2;
    float* bqkv = (float*)p; p += 3072 * 4;
    float* ctx  = (float*)p; p += 16384 * 4;   // ctx + Sk contiguous (one memset)
    float* Sk   = (float*)p; p += 512 * 4;

    hipLaunchKernelGGL(conv_weights, dim3(8333), dim3(256), 0, stream,
                       Wq, Wk, Wv, Wo, fw1, fw2, Wx_w, bq, bk, bv,
                       wqkv_t, wo_t, w1_t, w2_t, wx_bf, bqkv);
    hipLaunchKernelGGL(conv_x, dim3(NTOK / 32, CIN / 32, BATCH), dim3(256), 0, stream,
                       x, xbf);

    // input 1x1x1 conv + relu -> tA f32 + tbf bf16
    hipLaunchKernelGGL((gemm_bf16<1, 2>), dim3(216, 2, 1), dim3(256), 0, stream,
                       xbf, CIN, wx_bf, CIN, Wx_b, tA, tbf, 256, CIN,
                       (long)0, (long)0, (long)0);

    for (int i = 0; i < NLAYERS; ++i) {
        float* tin  = (i & 1) ? tB : tA;
        float* tout = (i & 1) ? tA : tB;

        // fused QKV: [M,256] x [256,768]
        hipLaunchKernelGGL((gemm_bf16<0, 1>), dim3(216, 6, 1), dim3(256), 0, stream,
                           tbf, 256, wqkv_t + (size_t)i * 196608, 256,
                           bqkv + i * 768, nullptr, qkv, 768, 256,
                           (long)0, (long)0, (long)0);

        // ctx (+ Sk) accumulate; no max-shift needed (|k| << 80)
        hipMemsetAsync(ctx, 0, (16384 + 512) * sizeof(float), stream);
        hipLaunchKernelGGL(ctx_kernel, dim3(27, NHEAD, BATCH), dim3(256), 0, stream,
                           qkv, ctx, Sk);

        // q softmax in place + W' = (ctx/Sk) @ Wo (per batch)
        hipLaunchKernelGGL(qsm_kernel, dim3(3456), dim3(256), 0, stream, qkv);
        hipLaunchKernelGGL(ctxwo_kernel, dim3(NHEAD, BATCH), dim3(256), 0, stream,
                           ctx, Sk, wo_t + (size_t)i * 65536, wp);

        // o_proj = qs @ W' + bo  (batched over z)
        hipLaunchKernelGGL((gemm_bf16<0, 1>), dim3(108, 2, BATCH), dim3(256), 0, stream,
                           qkv, 768, wp, 256, bo + i * 256, nullptr, ob, 256, 256,
                           (long)NTOK * 768, (long)65536, (long)NTOK * 256);

        hipLaunchKernelGGL((ln_kernel<1>), dim3(MTOT), dim3(256), 0, stream,
                           tin, ob, ln1_g + i * 256, ln1_b + i * 256, tbf);

        // FFN
        hipLaunchKernelGGL((gemm_bf16<2, 1>), dim3(216, 4, 1), dim3(256), 0, stream,
                           tbf, 256, w1_t + (size_t)i * 131072, 256,
                           fb1 + i * 512, nullptr, hbf, 512, 256,
                           (long)0, (long)0, (long)0);
        hipLaunchKernelGGL((gemm_bf16<0, 1>), dim3(216, 2, 1), dim3(256), 0, stream,
                           hbf, 512, w2_t + (size_t)i * 131072, 512,
                           fb2 + i * 256, nullptr, ob, 256, 512,
                           (long)0, (long)0, (long)0);
        hipLaunchKernelGGL((ln_kernel<0>), dim3(MTOT), dim3(256), 0, stream,
                           tin, ob, ln2_g + i * 256, ln2_b + i * 256, nullptr);

        // depthwise conv + residual -> tout f32 (+ tbf bf16 except last layer)
        if (i < NLAYERS - 1)
            hipLaunchKernelGGL((posconv_kernel<1>), dim3(576, BATCH), dim3(256), 0, stream,
                               tin, pw + (size_t)i * 6912, pb + i * 256, tout, tbf);
        else
            hipLaunchKernelGGL((posconv_kernel<0>), dim3(576, BATCH), dim3(256), 0, stream,
                               tin, pw + (size_t)i * 6912, pb + i * 256, tout, nullptr);
    }

    // layer 3 wrote tA
    hipLaunchKernelGGL(tr_out, dim3(MTOT / 32, 8), dim3(256), 0, stream, tA, out);
}